// Round 11
// baseline (219.121 us; speedup 1.0000x reference)
//
#include <hip/hip_runtime.h>

#define DEV __device__ __forceinline__

typedef __attribute__((ext_vector_type(4))) float f32x4;
typedef __attribute__((ext_vector_type(8))) short s16x8;

constexpr int B_ = 4, N_ = 4096, D_ = 1024;

DEV float elu1f(float x) { return x > 0.f ? x + 1.f : __expf(x); }
DEV unsigned short f2bf(float x) {            // RNE fp32 -> bf16
  unsigned u = __float_as_uint(x);
  return (unsigned short)((u + 0x7fffu + ((u >> 16) & 1u)) >> 16);
}
DEV float bf2f(unsigned short h) { return __uint_as_float(((unsigned)h) << 16); }

// ---------------- prep q: elu+1 -> bf16, linear ----------------
__global__ __launch_bounds__(256) void k_prep_q(const float* __restrict__ src,
                                                unsigned short* __restrict__ dst) {
  int n = B_ * N_ * D_ / 4;
  int stride = gridDim.x * blockDim.x;
  for (int i = blockIdx.x * blockDim.x + threadIdx.x; i < n; i += stride) {
    f32x4 x = ((const f32x4*)src)[i];
    unsigned long long r =
        (unsigned long long)((unsigned)f2bf(elu1f(x[0])) | ((unsigned)f2bf(elu1f(x[1])) << 16)) |
        ((unsigned long long)((unsigned)f2bf(elu1f(x[2])) | ((unsigned)f2bf(elu1f(x[3])) << 16)) << 32);
    ((unsigned long long*)dst)[i] = r;
  }
}

// ---------------- prep k,v: elu(k)+1, transpose to [D][N] bf16; fused ksum partials ----------------
// (v9 form; 6 variants measured 58-66us -> treated as this kernel's empirical floor.)
__global__ __launch_bounds__(256) void k_prep_tr(const float* __restrict__ K, const float* __restrict__ V,
                                                 unsigned short* __restrict__ kT, unsigned short* __restrict__ vT,
                                                 float* __restrict__ kspart) {
  __shared__ unsigned short T[64 * 68];        // [n][d] tile, stride 68
  int bid = blockIdx.x;
  int z = bid >> 12;
  int r = bid & 4095;
  int b = r >> 10, nb = (r >> 4) & 63, db = r & 15;
  const float* src = (z ? V : K) + ((size_t)b * N_ + nb * 64) * D_ + db * 64;
  unsigned short* dst = (z ? vT : kT) + ((size_t)b * D_ + db * 64) * N_ + nb * 64;
  int t = threadIdx.x;
  int nr = t >> 4, dc = (t & 15) * 4;
  #pragma unroll
  for (int u = 0; u < 4; ++u) {
    int n = nr + u * 16;
    f32x4 x = *(const f32x4*)(src + (size_t)n * D_ + dc);
    if (z == 0) { x[0] = elu1f(x[0]); x[1] = elu1f(x[1]); x[2] = elu1f(x[2]); x[3] = elu1f(x[3]); }
    unsigned long long pk =
        (unsigned long long)((unsigned)f2bf(x[0]) | ((unsigned)f2bf(x[1]) << 16)) |
        ((unsigned long long)((unsigned)f2bf(x[2]) | ((unsigned)f2bf(x[3]) << 16)) << 32);
    *(unsigned long long*)&T[n * 68 + dc] = pk;
  }
  __syncthreads();
  int dl = t >> 3, nc = (t & 7) * 8;           // row-group lane map: 8 lanes cover one 128B row
  #pragma unroll
  for (int p = 0; p < 2; ++p) {
    int d = p * 32 + dl;
    unsigned short tmp[8];
    float s = 0.f;
    #pragma unroll
    for (int j = 0; j < 8; ++j) { unsigned short h = T[(nc + j) * 68 + d]; tmp[j] = h; s += bf2f(h); }
    *(s16x8*)(dst + (size_t)d * N_ + nc) = *(s16x8*)&tmp[0];
    if (z == 0) {
      s += __shfl_xor(s, 1, 64);
      s += __shfl_xor(s, 2, 64);
      s += __shfl_xor(s, 4, 64);
      if ((t & 7) == 0) kspart[((size_t)b * 64 + nb) * D_ + db * 64 + d] = s;
    }
  }
}

// ---------------- GEMM machinery: 128x64 tile, BK=64, glds + XOR swizzle, 48KB LDS ----------------
// J = chunks-per-thread (rows/32): 4 for the 128-row A panel, 2 for the 64-row B panel.
template <int J>
DEV void stageT(const unsigned short* __restrict__ G, long sG, unsigned short* L, int t, int kofs) {
  #pragma unroll
  for (int j = 0; j < J; ++j) {
    int q = j * 256 + t;
    int r = q >> 3;
    int c = (q & 7) ^ (r & 7);
    const unsigned short* g = G + (size_t)r * sG + kofs + c * 8;
    unsigned short* l = L + (q & ~63) * 8;     // wave-uniform base; HW adds lane*16
    __builtin_amdgcn_global_load_lds((const __attribute__((address_space(1))) unsigned int*)(const void*)g,
                                     (__attribute__((address_space(3))) unsigned int*)(void*)l, 16, 0, 0);
  }
}

// 4 waves as 2(M) x 2(N): wave owns 64 A-rows x 32 B-rows.
DEV void mac64(const unsigned short* LA, const unsigned short* LB, int lane, int wm, int wn,
               f32x4 (&acc)[4][2]) {
  int rr = lane & 15, cq = lane >> 4;
  #pragma unroll
  for (int ks = 0; ks < 2; ++ks) {
    s16x8 af[4], bf[2];
    #pragma unroll
    for (int m = 0; m < 4; ++m) {
      int row = wm * 64 + m * 16 + rr;
      af[m] = *(const s16x8*)&LA[row * 64 + ((ks * 4 + cq) ^ (rr & 7)) * 8];
    }
    #pragma unroll
    for (int n = 0; n < 2; ++n) {
      int row = wn * 32 + n * 16 + rr;
      bf[n] = *(const s16x8*)&LB[row * 64 + ((ks * 4 + cq) ^ (rr & 7)) * 8];
    }
    #pragma unroll
    for (int m = 0; m < 4; ++m)
      #pragma unroll
      for (int n = 0; n < 2; ++n)
        acc[m][n] = __builtin_amdgcn_mfma_f32_16x16x32_bf16(af[m], bf[n], acc[m][n], 0, 0, 0);
  }
}

// ---------------- GEMM1 (128d x 64e tiles, 1024 blocks, 3 blocks/CU) + ksum2 tail ----------------
__global__ __launch_bounds__(256, 3) void k_g1(const unsigned short* __restrict__ kT,
                                               const unsigned short* __restrict__ vT,
                                               float* __restrict__ part,
                                               const float* __restrict__ kspart,
                                               float* __restrict__ ksum) {
  __shared__ unsigned short LA[2][8192], LB[2][4096];   // 32KB + 16KB
  int bid = blockIdx.x;
  if (bid >= 1024) {                           // ---- ksum2 path (16 blocks) ----
    int idx = (bid - 1024) * 256 + threadIdx.x; // 4096 = b*1024 + d
    int b = idx >> 10, d = idx & 1023;
    float a = 0.f;
    #pragma unroll 8
    for (int s = 0; s < 64; ++s) a += kspart[((size_t)b * 64 + s) * D_ + d];
    ksum[idx] = a;
    return;
  }
  int e = bid & 15, dl = (bid >> 4) & 7, cb = bid >> 7;  // e(16 x 64), dl(8 x 128), cb = kc*4+b
  int kc = cb >> 2, b = cb & 3;
  int d0 = dl * 128, e0 = e * 64;
  const unsigned short* A  = kT + ((size_t)b * D_ + d0) * N_ + kc * 2048;
  const unsigned short* Bp = vT + ((size_t)b * D_ + e0) * N_ + kc * 2048;
  int t = threadIdx.x, lane = t & 63, wid = t >> 6, wm = wid >> 1, wn = wid & 1;
  f32x4 acc[4][2] = {};
  stageT<4>(A, N_, LA[0], t, 0);
  stageT<2>(Bp, N_, LB[0], t, 0);
  asm volatile("s_waitcnt vmcnt(0)" ::: "memory");
  __syncthreads();
  int cur = 0;
  for (int it = 0; it < 32; ++it) {
    if (it < 31) {
      stageT<4>(A, N_, LA[cur ^ 1], t, (it + 1) * 64);
      stageT<2>(Bp, N_, LB[cur ^ 1], t, (it + 1) * 64);
    }
    mac64(LA[cur], LB[cur], lane, wm, wn, acc);
    asm volatile("s_waitcnt vmcnt(0)" ::: "memory");
    __syncthreads();
    cur ^= 1;
  }
  float* P = part + ((size_t)cb << 20) + (size_t)d0 * D_ + e0;
  int rq = (lane >> 4) * 4, cc = lane & 15;
  #pragma unroll
  for (int m = 0; m < 4; ++m)
    #pragma unroll
    for (int r = 0; r < 4; ++r) {
      int row = wm * 64 + m * 16 + rq + r;
      #pragma unroll
      for (int n = 0; n < 2; ++n)
        P[(size_t)row * D_ + wn * 32 + n * 16 + cc] = acc[m][n][r];
    }
}

// ---------------- reduce + denom tail blocks ----------------
__global__ __launch_bounds__(256) void k_rd(const float* __restrict__ part,
                                            unsigned short* __restrict__ kvT,
                                            const unsigned short* __restrict__ qp,
                                            const float* __restrict__ ksum,
                                            float* __restrict__ den) {
  __shared__ unsigned T[64 * 36];              // [e][36] dwords: 32 d-pair dwords + 4 pad
  int bid = blockIdx.x;
  if (bid >= 1024) {                           // ---- denom path ----
    int wid = threadIdx.x >> 6, lane = threadIdx.x & 63;
    int row = (bid - 1024) * 4 + wid;          // [0, B*N)
    int b = row >> 12;
    const unsigned short* qr = qp + (size_t)row * D_ + lane * 16;
    const float* ks = ksum + b * D_ + lane * 16;
    s16x8 h0 = *(const s16x8*)qr;
    s16x8 h1 = *(const s16x8*)(qr + 8);
    float acc = 0.f;
    #pragma unroll
    for (int j = 0; j < 8; ++j) acc += bf2f((unsigned short)h0[j]) * ks[j];
    #pragma unroll
    for (int j = 0; j < 8; ++j) acc += bf2f((unsigned short)h1[j]) * ks[8 + j];
    #pragma unroll
    for (int o = 32; o; o >>= 1) acc += __shfl_down(acc, o, 64);
    if (!lane) den[row] = acc;
    return;
  }
  // ---- reduce path (dword-pair LDS transpose) ----
  int b = bid >> 8, eb = (bid >> 4) & 15, db = bid & 15;
  const float* p0 = part + ((size_t)b << 20) + (size_t)(db * 64) * D_ + eb * 64;
  const float* p1 = p0 + ((size_t)4 << 20);
  int t = threadIdx.x;
  int d0 = (t >> 4) * 4, ec = (t & 15) * 4;    // wave reads 256B/row
  f32x4 a0 = *(const f32x4*)(p0 + (size_t)d0 * D_ + ec)       + *(const f32x4*)(p1 + (size_t)d0 * D_ + ec);
  f32x4 a1 = *(const f32x4*)(p0 + (size_t)(d0 + 1) * D_ + ec) + *(const f32x4*)(p1 + (size_t)(d0 + 1) * D_ + ec);
  f32x4 a2 = *(const f32x4*)(p0 + (size_t)(d0 + 2) * D_ + ec) + *(const f32x4*)(p1 + (size_t)(d0 + 2) * D_ + ec);
  f32x4 a3 = *(const f32x4*)(p0 + (size_t)(d0 + 3) * D_ + ec) + *(const f32x4*)(p1 + (size_t)(d0 + 3) * D_ + ec);
  #pragma unroll
  for (int j = 0; j < 4; ++j) {
    unsigned lo = (unsigned)f2bf(a0[j]) | ((unsigned)f2bf(a1[j]) << 16);
    unsigned hi = (unsigned)f2bf(a2[j]) | ((unsigned)f2bf(a3[j]) << 16);
    *(unsigned long long*)&T[(ec + j) * 36 + d0 / 2] =
        (unsigned long long)lo | ((unsigned long long)hi << 32);
  }
  __syncthreads();
  int e = t >> 2, cc = t & 3;
  unsigned short* dstb = kvT + ((size_t)b * D_ + eb * 64 + e) * D_ + db * 64;
  #pragma unroll
  for (int m = 0; m < 2; ++m) {
    s16x8 w = *(const s16x8*)&T[e * 36 + cc * 8 + m * 4];
    *(s16x8*)(dstb + cc * 16 + m * 8) = w;
  }
}

// ---------------- GEMM2 (128n x 64e tiles, 2048 blocks, 3 blocks/CU) ----------------
__global__ __launch_bounds__(256, 3) void k_gemm2(const unsigned short* __restrict__ qp,
                                                  const unsigned short* __restrict__ kvT,
                                                  const float* __restrict__ den,
                                                  float* __restrict__ out) {
  __shared__ unsigned short LA[2][8192], LB[2][4096];   // 32KB + 16KB
  int bid = blockIdx.x;
  int e = bid & 15, ml = (bid >> 4) & 31, b = bid >> 9;  // e(16 x 64), ml(32 x 128), b(4)
  int m0 = ml * 128, e0 = e * 64;
  const unsigned short* A  = qp  + ((size_t)b * N_ + m0) * D_;
  const unsigned short* Bp = kvT + ((size_t)b * D_ + e0) * D_;
  int t = threadIdx.x, lane = t & 63, wid = t >> 6, wm = wid >> 1, wn = wid & 1;
  f32x4 acc[4][2] = {};
  stageT<4>(A, D_, LA[0], t, 0);
  stageT<2>(Bp, D_, LB[0], t, 0);
  asm volatile("s_waitcnt vmcnt(0)" ::: "memory");
  __syncthreads();
  int cur = 0;
  for (int it = 0; it < 16; ++it) {
    if (it < 15) {
      stageT<4>(A, D_, LA[cur ^ 1], t, (it + 1) * 64);
      stageT<2>(Bp, D_, LB[cur ^ 1], t, (it + 1) * 64);
    }
    mac64(LA[cur], LB[cur], lane, wm, wn, acc);
    asm volatile("s_waitcnt vmcnt(0)" ::: "memory");
    __syncthreads();
    cur ^= 1;
  }
  const float* dn = den + b * N_ + m0;
  float* ob = out + ((size_t)b * N_ + m0) * D_ + e0;
  int rq = (lane >> 4) * 4, cc = lane & 15;
  #pragma unroll
  for (int m = 0; m < 4; ++m)
    #pragma unroll
    for (int r = 0; r < 4; ++r) {
      int row = wm * 64 + m * 16 + rq + r;
      float inv = 1.f / (dn[row] + 1e-6f);
      #pragma unroll
      for (int n = 0; n < 2; ++n)
        ob[(size_t)row * D_ + wn * 32 + n * 16 + cc] = acc[m][n][r] * inv;
    }
}

extern "C" void kernel_launch(void* const* d_in, const int* in_sizes, int n_in,
                              void* d_out, int out_size, void* d_ws, size_t ws_size,
                              hipStream_t stream) {
  const float* q = (const float*)d_in[0];
  const float* k = (const float*)d_in[1];
  const float* v = (const float*)d_in[2];
  float* outF = (float*)d_out;
  char* ws = (char*)d_ws;

  // ws: qp 32MB | kT 32MB | vT 32MB | kvT 8MB | ksum 16KB | den 64KB  (= 104.1MB)
  unsigned short* qp  = (unsigned short*)ws;
  unsigned short* kT  = (unsigned short*)(ws + ((size_t)32 << 20));
  unsigned short* vT  = (unsigned short*)(ws + ((size_t)64 << 20));
  unsigned short* kvT = (unsigned short*)(ws + ((size_t)96 << 20));
  float* ksum = (float*)(ws + ((size_t)104 << 20));
  float* den  = (float*)(ws + ((size_t)104 << 20) + 16384);
  // d_out doubles as scratch (fully overwritten by k_gemm2 afterwards):
  float* part   = outF;                 // 2 x 16MB fp32 kv partials
  float* kspart = outF + (8 << 20);     // 1MB ksum partials at +32MB

  k_prep_tr<<<8192, 256, 0, stream>>>(k, v, kT, vT, kspart);
  k_prep_q <<<1024, 256, 0, stream>>>(q, qp);
  k_g1     <<<1040, 256, 0, stream>>>(kT, vT, part, kspart, ksum);
  k_rd     <<<5120, 256, 0, stream>>>(part, kvT, qp, ksum, den);
  k_gemm2  <<<2048, 256, 0, stream>>>(qp, kvT, den, outF);
}

// Round 12
// 180.968 us; speedup vs baseline: 1.2108x; 1.2108x over previous
//
#include <hip/hip_runtime.h>

#define DEV __device__ __forceinline__

typedef __attribute__((ext_vector_type(4))) float f32x4;
typedef __attribute__((ext_vector_type(8))) short s16x8;

constexpr int B_ = 4, N_ = 4096, D_ = 1024;

DEV float elu1f(float x) { return x > 0.f ? x + 1.f : __expf(x); }
DEV unsigned short f2bf(float x) {            // RNE fp32 -> bf16
  unsigned u = __float_as_uint(x);
  return (unsigned short)((u + 0x7fffu + ((u >> 16) & 1u)) >> 16);
}
DEV float bf2f(unsigned short h) { return __uint_as_float(((unsigned)h) << 16); }

// ---------------- prep q: elu+1 -> bf16, linear ----------------
__global__ __launch_bounds__(256) void k_prep_q(const float* __restrict__ src,
                                                unsigned short* __restrict__ dst) {
  int n = B_ * N_ * D_ / 4;
  int stride = gridDim.x * blockDim.x;
  for (int i = blockIdx.x * blockDim.x + threadIdx.x; i < n; i += stride) {
    f32x4 x = ((const f32x4*)src)[i];
    unsigned long long r =
        (unsigned long long)((unsigned)f2bf(elu1f(x[0])) | ((unsigned)f2bf(elu1f(x[1])) << 16)) |
        ((unsigned long long)((unsigned)f2bf(elu1f(x[2])) | ((unsigned)f2bf(elu1f(x[3])) << 16)) << 32);
    ((unsigned long long*)dst)[i] = r;
  }
}

// ---------------- prep k,v: elu(k)+1, transpose to [D][N] bf16; fused ksum partials ----------------
// (v9 form; 6 variants measured 58-66us -> treated as this kernel's empirical floor.)
__global__ __launch_bounds__(256) void k_prep_tr(const float* __restrict__ K, const float* __restrict__ V,
                                                 unsigned short* __restrict__ kT, unsigned short* __restrict__ vT,
                                                 float* __restrict__ kspart) {
  __shared__ unsigned short T[64 * 68];        // [n][d] tile, stride 68
  int bid = blockIdx.x;
  int z = bid >> 12;
  int r = bid & 4095;
  int b = r >> 10, nb = (r >> 4) & 63, db = r & 15;
  const float* src = (z ? V : K) + ((size_t)b * N_ + nb * 64) * D_ + db * 64;
  unsigned short* dst = (z ? vT : kT) + ((size_t)b * D_ + db * 64) * N_ + nb * 64;
  int t = threadIdx.x;
  int nr = t >> 4, dc = (t & 15) * 4;
  #pragma unroll
  for (int u = 0; u < 4; ++u) {
    int n = nr + u * 16;
    f32x4 x = *(const f32x4*)(src + (size_t)n * D_ + dc);
    if (z == 0) { x[0] = elu1f(x[0]); x[1] = elu1f(x[1]); x[2] = elu1f(x[2]); x[3] = elu1f(x[3]); }
    unsigned long long pk =
        (unsigned long long)((unsigned)f2bf(x[0]) | ((unsigned)f2bf(x[1]) << 16)) |
        ((unsigned long long)((unsigned)f2bf(x[2]) | ((unsigned)f2bf(x[3]) << 16)) << 32);
    *(unsigned long long*)&T[n * 68 + dc] = pk;
  }
  __syncthreads();
  int dl = t >> 3, nc = (t & 7) * 8;           // row-group lane map: 8 lanes cover one 128B row
  #pragma unroll
  for (int p = 0; p < 2; ++p) {
    int d = p * 32 + dl;
    unsigned short tmp[8];
    float s = 0.f;
    #pragma unroll
    for (int j = 0; j < 8; ++j) { unsigned short h = T[(nc + j) * 68 + d]; tmp[j] = h; s += bf2f(h); }
    *(s16x8*)(dst + (size_t)d * N_ + nc) = *(s16x8*)&tmp[0];
    if (z == 0) {
      s += __shfl_xor(s, 1, 64);
      s += __shfl_xor(s, 2, 64);
      s += __shfl_xor(s, 4, 64);
      if ((t & 7) == 0) kspart[((size_t)b * 64 + nb) * D_ + db * 64 + d] = s;
    }
  }
}

// ---------------- shared GEMM machinery: 128x128 tile, BK=64, glds + XOR swizzle ----------------
DEV void stage8(const unsigned short* __restrict__ A, const unsigned short* __restrict__ Bp,
                long sA, long sB, unsigned short* LA, unsigned short* LB, int t, int kofs) {
  #pragma unroll
  for (int j = 0; j < 4; ++j) {
    int q = j * 256 + t;
    int r = q >> 3;
    int c = (q & 7) ^ (r & 7);
    const unsigned short* g = A + (size_t)r * sA + kofs + c * 8;
    unsigned short* l = LA + (q & ~63) * 8;    // wave-uniform base; HW adds lane*16
    __builtin_amdgcn_global_load_lds((const __attribute__((address_space(1))) unsigned int*)(const void*)g,
                                     (__attribute__((address_space(3))) unsigned int*)(void*)l, 16, 0, 0);
  }
  #pragma unroll
  for (int j = 0; j < 4; ++j) {
    int q = j * 256 + t;
    int r = q >> 3;
    int c = (q & 7) ^ (r & 7);
    const unsigned short* g = Bp + (size_t)r * sB + kofs + c * 8;
    unsigned short* l = LB + (q & ~63) * 8;
    __builtin_amdgcn_global_load_lds((const __attribute__((address_space(1))) unsigned int*)(const void*)g,
                                     (__attribute__((address_space(3))) unsigned int*)(void*)l, 16, 0, 0);
  }
}

DEV void mac128(const unsigned short* LA, const unsigned short* LB, int lane, int wm, int wn,
                f32x4 (&acc)[4][4]) {
  int rr = lane & 15, cq = lane >> 4;
  #pragma unroll
  for (int ks = 0; ks < 2; ++ks) {
    s16x8 af[4], bf[4];
    #pragma unroll
    for (int m = 0; m < 4; ++m) {
      int row = wm * 64 + m * 16 + rr;
      af[m] = *(const s16x8*)&LA[row * 64 + ((ks * 4 + cq) ^ (rr & 7)) * 8];
    }
    #pragma unroll
    for (int n = 0; n < 4; ++n) {
      int row = wn * 64 + n * 16 + rr;
      bf[n] = *(const s16x8*)&LB[row * 64 + ((ks * 4 + cq) ^ (rr & 7)) * 8];
    }
    #pragma unroll
    for (int m = 0; m < 4; ++m)
      #pragma unroll
      for (int n = 0; n < 4; ++n)
        acc[m][n] = __builtin_amdgcn_mfma_f32_16x16x32_bf16(af[m], bf[n], acc[m][n], 0, 0, 0);
  }
}

// ---------------- GEMM1: kc=4 K-split, 128x128 tile, SINGLE-buffer 32KB LDS, 4 blocks/CU ----------------
// 1024 gemm blocks (e(8) x dl(8) x cb(16), cb = kc*4+b) + 16 ksum2 tail blocks.
// part[cb] slices: 16 x 4MB fp32 = 64MB = d_out exactly. m97-structure loop (2 barriers,
// vmcnt(0) drain) - inter-block overlap at 4/CU provides the load/compute pipelining.
__global__ __launch_bounds__(256, 4) void k_g1(const unsigned short* __restrict__ kT,
                                               const unsigned short* __restrict__ vT,
                                               float* __restrict__ part,
                                               const float* __restrict__ kspart,
                                               float* __restrict__ ksum) {
  __shared__ unsigned short LA[8192], LB[8192];  // 32KB total
  int bid = blockIdx.x;
  if (bid >= 1024) {                           // ---- ksum2 path (16 blocks) ----
    int idx = (bid - 1024) * 256 + threadIdx.x; // 4096 = b*1024 + d
    int b = idx >> 10, d = idx & 1023;
    float a = 0.f;
    #pragma unroll 8
    for (int s = 0; s < 64; ++s) a += kspart[((size_t)b * 64 + s) * D_ + d];
    ksum[idx] = a;
    return;
  }
  int e = bid & 7, dl = (bid >> 3) & 7, cb = bid >> 6;   // cb = kc*4+b in [0,16)
  int kc = cb >> 2, b = cb & 3;
  int d0 = dl * 128, e0 = e * 128;
  const unsigned short* A  = kT + ((size_t)b * D_ + d0) * N_ + kc * 1024;
  const unsigned short* Bp = vT + ((size_t)b * D_ + e0) * N_ + kc * 1024;
  int t = threadIdx.x, lane = t & 63, wid = t >> 6, wm = wid >> 1, wn = wid & 1;
  f32x4 acc[4][4] = {};
  stage8(A, Bp, N_, N_, LA, LB, t, 0);
  for (int it = 0; it < 16; ++it) {
    asm volatile("s_waitcnt vmcnt(0)" ::: "memory");
    __syncthreads();                           // staged tile visible
    mac128(LA, LB, lane, wm, wn, acc);
    __syncthreads();                           // all reads done before overwrite
    if (it < 15) stage8(A, Bp, N_, N_, LA, LB, t, (it + 1) * 64);
  }
  float* P = part + ((size_t)cb << 20) + (size_t)d0 * D_ + e0;
  int rq = (lane >> 4) * 4, cc = lane & 15;
  #pragma unroll
  for (int m = 0; m < 4; ++m)
    #pragma unroll
    for (int r = 0; r < 4; ++r) {
      int row = wm * 64 + m * 16 + rq + r;
      #pragma unroll
      for (int n = 0; n < 4; ++n)
        P[(size_t)row * D_ + wn * 64 + n * 16 + cc] = acc[m][n][r];
    }
}

// ---------------- reduce (4 partials) + denom tail blocks ----------------
__global__ __launch_bounds__(256) void k_rd(const float* __restrict__ part,
                                            unsigned short* __restrict__ kvT,
                                            const unsigned short* __restrict__ qp,
                                            const float* __restrict__ ksum,
                                            float* __restrict__ den) {
  __shared__ unsigned T[64 * 36];              // [e][36] dwords: 32 d-pair dwords + 4 pad
  int bid = blockIdx.x;
  if (bid >= 1024) {                           // ---- denom path ----
    int wid = threadIdx.x >> 6, lane = threadIdx.x & 63;
    int row = (bid - 1024) * 4 + wid;          // [0, B*N)
    int b = row >> 12;
    const unsigned short* qr = qp + (size_t)row * D_ + lane * 16;
    const float* ks = ksum + b * D_ + lane * 16;
    s16x8 h0 = *(const s16x8*)qr;
    s16x8 h1 = *(const s16x8*)(qr + 8);
    float acc = 0.f;
    #pragma unroll
    for (int j = 0; j < 8; ++j) acc += bf2f((unsigned short)h0[j]) * ks[j];
    #pragma unroll
    for (int j = 0; j < 8; ++j) acc += bf2f((unsigned short)h1[j]) * ks[8 + j];
    #pragma unroll
    for (int o = 32; o; o >>= 1) acc += __shfl_down(acc, o, 64);
    if (!lane) den[row] = acc;
    return;
  }
  // ---- reduce path: kvT[b,e,d] = bf16(sum of 4 kc-partials), transposed via LDS ----
  int b = bid >> 8, eb = (bid >> 4) & 15, db = bid & 15;
  const float* p0 = part + ((size_t)b << 20)        + (size_t)(db * 64) * D_ + eb * 64;
  const float* p1 = part + ((size_t)(4 + b) << 20)  + (size_t)(db * 64) * D_ + eb * 64;
  const float* p2 = part + ((size_t)(8 + b) << 20)  + (size_t)(db * 64) * D_ + eb * 64;
  const float* p3 = part + ((size_t)(12 + b) << 20) + (size_t)(db * 64) * D_ + eb * 64;
  int t = threadIdx.x;
  int d0 = (t >> 4) * 4, ec = (t & 15) * 4;    // wave reads 256B/row
  f32x4 a0, a1, a2, a3;
  #pragma unroll
  for (int r = 0; r < 4; ++r) {
    size_t o = (size_t)(d0 + r) * D_ + ec;
    f32x4 s = *(const f32x4*)(p0 + o) + *(const f32x4*)(p1 + o) +
              *(const f32x4*)(p2 + o) + *(const f32x4*)(p3 + o);
    if (r == 0) a0 = s; else if (r == 1) a1 = s; else if (r == 2) a2 = s; else a3 = s;
  }
  #pragma unroll
  for (int j = 0; j < 4; ++j) {
    unsigned lo = (unsigned)f2bf(a0[j]) | ((unsigned)f2bf(a1[j]) << 16);
    unsigned hi = (unsigned)f2bf(a2[j]) | ((unsigned)f2bf(a3[j]) << 16);
    *(unsigned long long*)&T[(ec + j) * 36 + d0 / 2] =
        (unsigned long long)lo | ((unsigned long long)hi << 32);
  }
  __syncthreads();
  int e = t >> 2, cc = t & 3;
  unsigned short* dstb = kvT + ((size_t)b * D_ + eb * 64 + e) * D_ + db * 64;
  #pragma unroll
  for (int m = 0; m < 2; ++m) {
    s16x8 w = *(const s16x8*)&T[e * 36 + cc * 8 + m * 4];
    *(s16x8*)(dstb + cc * 16 + m * 8) = w;
  }
}

// ---------------- GEMM2: 128x128 tile, SINGLE-buffer 32KB LDS, 1024 blocks = 4 blocks/CU ----------------
__global__ __launch_bounds__(256, 4) void k_gemm2(const unsigned short* __restrict__ qp,
                                                  const unsigned short* __restrict__ kvT,
                                                  const float* __restrict__ den,
                                                  float* __restrict__ out) {
  __shared__ unsigned short LA[8192], LB[8192];  // 32KB total
  int bid = blockIdx.x;
  int b = (bid & 7) >> 1, mh = bid & 1, sg = bid >> 3;
  int ml = sg & 15, e = sg >> 4;
  int m0 = (mh * 16 + ml) * 128, e0 = e * 128;
  const unsigned short* A  = qp  + ((size_t)b * N_ + m0) * D_;
  const unsigned short* Bp = kvT + ((size_t)b * D_ + e0) * D_;
  int t = threadIdx.x, lane = t & 63, wid = t >> 6, wm = wid >> 1, wn = wid & 1;
  f32x4 acc[4][4] = {};
  stage8(A, Bp, D_, D_, LA, LB, t, 0);
  for (int it = 0; it < 16; ++it) {
    asm volatile("s_waitcnt vmcnt(0)" ::: "memory");
    __syncthreads();
    mac128(LA, LB, lane, wm, wn, acc);
    __syncthreads();
    if (it < 15) stage8(A, Bp, D_, D_, LA, LB, t, (it + 1) * 64);
  }
  const float* dn = den + b * N_ + m0;
  float* ob = out + ((size_t)b * N_ + m0) * D_ + e0;
  int rq = (lane >> 4) * 4, cc = lane & 15;
  #pragma unroll
  for (int m = 0; m < 4; ++m)
    #pragma unroll
    for (int r = 0; r < 4; ++r) {
      int row = wm * 64 + m * 16 + rq + r;
      float inv = 1.f / (dn[row] + 1e-6f);
      #pragma unroll
      for (int n = 0; n < 4; ++n)
        ob[(size_t)row * D_ + wn * 64 + n * 16 + cc] = acc[m][n][r] * inv;
    }
}

extern "C" void kernel_launch(void* const* d_in, const int* in_sizes, int n_in,
                              void* d_out, int out_size, void* d_ws, size_t ws_size,
                              hipStream_t stream) {
  const float* q = (const float*)d_in[0];
  const float* k = (const float*)d_in[1];
  const float* v = (const float*)d_in[2];
  float* outF = (float*)d_out;
  char* ws = (char*)d_ws;

  // ws: qp 32MB | kT 32MB | vT 32MB | kvT 8MB | ksum 16KB | den 64KB | kspart 1MB (= 105.1MB)
  unsigned short* qp  = (unsigned short*)ws;
  unsigned short* kT  = (unsigned short*)(ws + ((size_t)32 << 20));
  unsigned short* vT  = (unsigned short*)(ws + ((size_t)64 << 20));
  unsigned short* kvT = (unsigned short*)(ws + ((size_t)96 << 20));
  float* ksum   = (float*)(ws + ((size_t)104 << 20));
  float* den    = (float*)(ws + ((size_t)104 << 20) + 16384);
  float* kspart = (float*)(ws + ((size_t)104 << 20) + 16384 + 65536);
  // d_out doubles as scratch (fully overwritten by k_gemm2 afterwards):
  float* part = outF;                  // 16 x 4MB fp32 kv partials = 64MB (fills d_out)

  k_prep_tr<<<8192, 256, 0, stream>>>(k, v, kT, vT, kspart);
  k_prep_q <<<1024, 256, 0, stream>>>(q, qp);
  k_g1     <<<1040, 256, 0, stream>>>(kT, vT, part, kspart, ksum);
  k_rd     <<<5120, 256, 0, stream>>>(part, kvT, qp, ksum, den);
  k_gemm2  <<<1024, 256, 0, stream>>>(qp, kvT, den, outF);
}

// Round 13
// 168.113 us; speedup vs baseline: 1.3034x; 1.0765x over previous
//
#include <hip/hip_runtime.h>

#define DEV __device__ __forceinline__

typedef __attribute__((ext_vector_type(4))) float f32x4;
typedef __attribute__((ext_vector_type(8))) short s16x8;

constexpr int B_ = 4, N_ = 4096, D_ = 1024;

DEV float elu1f(float x) { return x > 0.f ? x + 1.f : __expf(x); }
DEV unsigned short f2bf(float x) {            // RNE fp32 -> bf16
  unsigned u = __float_as_uint(x);
  return (unsigned short)((u + 0x7fffu + ((u >> 16) & 1u)) >> 16);
}
DEV float bf2f(unsigned short h) { return __uint_as_float(((unsigned)h) << 16); }

// ---------------- prep: K,V elu+transpose + q elu->bf16 stream (v7 verbatim, best-known) ----------------
// bid < 8192: z(2) * b(4) * nb(64) * db(16) transpose blocks (64n x 64d tile).
// bid >= 8192: 1024 grid-stride blocks doing q prep.
__global__ __launch_bounds__(256) void k_prep(const float* __restrict__ Q, const float* __restrict__ K,
                                              const float* __restrict__ V,
                                              unsigned short* __restrict__ qp, unsigned short* __restrict__ kT,
                                              unsigned short* __restrict__ vT, float* __restrict__ kspart) {
  __shared__ unsigned short T[64 * 68];        // [n][d] tile, stride 68
  int bid = blockIdx.x;
  if (bid >= 8192) {                           // ---- q-stream path ----
    int n = B_ * N_ * D_ / 4;
    int stride = 1024 * 256;
    for (int i = (bid - 8192) * 256 + threadIdx.x; i < n; i += stride) {
      f32x4 x = ((const f32x4*)Q)[i];
      unsigned long long r =
          (unsigned long long)((unsigned)f2bf(elu1f(x[0])) | ((unsigned)f2bf(elu1f(x[1])) << 16)) |
          ((unsigned long long)((unsigned)f2bf(elu1f(x[2])) | ((unsigned)f2bf(elu1f(x[3])) << 16)) << 32);
      ((unsigned long long*)qp)[i] = r;
    }
    return;
  }
  // ---- transpose path ----
  int z = bid >> 12;
  int r = bid & 4095;
  int b = r >> 10, nb = (r >> 4) & 63, db = r & 15;
  const float* src = (z ? V : K) + ((size_t)b * N_ + nb * 64) * D_ + db * 64;
  unsigned short* dst = (z ? vT : kT) + ((size_t)b * D_ + db * 64) * N_ + nb * 64;
  int t = threadIdx.x;
  int nr = t >> 4, dc = (t & 15) * 4;
  #pragma unroll
  for (int u = 0; u < 4; ++u) {
    int n = nr + u * 16;
    f32x4 x = *(const f32x4*)(src + (size_t)n * D_ + dc);
    if (z == 0) { x[0] = elu1f(x[0]); x[1] = elu1f(x[1]); x[2] = elu1f(x[2]); x[3] = elu1f(x[3]); }
    unsigned long long pk =
        (unsigned long long)((unsigned)f2bf(x[0]) | ((unsigned)f2bf(x[1]) << 16)) |
        ((unsigned long long)((unsigned)f2bf(x[2]) | ((unsigned)f2bf(x[3]) << 16)) << 32);
    *(unsigned long long*)&T[n * 68 + dc] = pk;
  }
  __syncthreads();
  int d = t >> 2, c = (t & 3) * 16;            // output row d (64), n-chunk c (4x16)
  unsigned short tmp[16];
  float s = 0.f;
  #pragma unroll
  for (int j = 0; j < 16; ++j) { unsigned short h = T[(c + j) * 68 + d]; tmp[j] = h; s += bf2f(h); }
  *(s16x8*)(dst + (size_t)d * N_ + c) = *(s16x8*)&tmp[0];
  *(s16x8*)(dst + (size_t)d * N_ + c + 8) = *(s16x8*)&tmp[8];
  if (z == 0) {                                 // fused ksum partial over this block's 64 n
    s += __shfl_xor(s, 1, 64);
    s += __shfl_xor(s, 2, 64);
    if ((t & 3) == 0) kspart[((size_t)b * 64 + nb) * D_ + db * 64 + d] = s;
  }
}

// ---------------- shared GEMM machinery: 128x128 tile, BK=64, glds + XOR swizzle ----------------
DEV void stage8(const unsigned short* __restrict__ A, const unsigned short* __restrict__ Bp,
                long sA, long sB, unsigned short* LA, unsigned short* LB, int t, int kofs) {
  #pragma unroll
  for (int j = 0; j < 4; ++j) {
    int q = j * 256 + t;
    int r = q >> 3;
    int c = (q & 7) ^ (r & 7);
    const unsigned short* g = A + (size_t)r * sA + kofs + c * 8;
    unsigned short* l = LA + (q & ~63) * 8;    // wave-uniform base; HW adds lane*16
    __builtin_amdgcn_global_load_lds((const __attribute__((address_space(1))) unsigned int*)(const void*)g,
                                     (__attribute__((address_space(3))) unsigned int*)(void*)l, 16, 0, 0);
  }
  #pragma unroll
  for (int j = 0; j < 4; ++j) {
    int q = j * 256 + t;
    int r = q >> 3;
    int c = (q & 7) ^ (r & 7);
    const unsigned short* g = Bp + (size_t)r * sB + kofs + c * 8;
    unsigned short* l = LB + (q & ~63) * 8;
    __builtin_amdgcn_global_load_lds((const __attribute__((address_space(1))) unsigned int*)(const void*)g,
                                     (__attribute__((address_space(3))) unsigned int*)(void*)l, 16, 0, 0);
  }
}

DEV void mac128(const unsigned short* LA, const unsigned short* LB, int lane, int wm, int wn,
                f32x4 (&acc)[4][4]) {
  int rr = lane & 15, cq = lane >> 4;
  #pragma unroll
  for (int ks = 0; ks < 2; ++ks) {
    s16x8 af[4], bf[4];
    #pragma unroll
    for (int m = 0; m < 4; ++m) {
      int row = wm * 64 + m * 16 + rr;
      af[m] = *(const s16x8*)&LA[row * 64 + ((ks * 4 + cq) ^ (rr & 7)) * 8];
    }
    #pragma unroll
    for (int n = 0; n < 4; ++n) {
      int row = wn * 64 + n * 16 + rr;
      bf[n] = *(const s16x8*)&LB[row * 64 + ((ks * 4 + cq) ^ (rr & 7)) * 8];
    }
    #pragma unroll
    for (int m = 0; m < 4; ++m)
      #pragma unroll
      for (int n = 0; n < 4; ++n)
        acc[m][n] = __builtin_amdgcn_mfma_f32_16x16x32_bf16(af[m], bf[n], acc[m][n], 0, 0, 0);
  }
}

// ---------------- GEMM1 + ksum2 tail blocks ----------------
// bid < 512: part[kc,b,d,e] = sum_{n in kc-half} k'T[d,n] vT[e,n], fp32.
// bid >= 512 (16 blocks): ksum[b,d] = sum of 64 kspart partials.
__global__ __launch_bounds__(256, 2) void k_g1(const unsigned short* __restrict__ kT,
                                               const unsigned short* __restrict__ vT,
                                               float* __restrict__ part,
                                               const float* __restrict__ kspart,
                                               float* __restrict__ ksum) {
  __shared__ unsigned short LA[2][8192], LB[2][8192];
  int bid = blockIdx.x;
  if (bid >= 512) {                            // ---- ksum2 path ----
    int idx = (bid - 512) * 256 + threadIdx.x; // 4096 = b*1024 + d
    int b = idx >> 10, d = idx & 1023;
    float a = 0.f;
    #pragma unroll 8
    for (int s = 0; s < 64; ++s) a += kspart[((size_t)b * 64 + s) * D_ + d];
    ksum[idx] = a;
    return;
  }
  int b = (bid & 7) >> 1, dh = bid & 1, sg = bid >> 3;
  int kc = sg & 1, dl = (sg >> 1) & 3, e = sg >> 3;
  int d0 = (dh * 4 + dl) * 128, e0 = e * 128;
  const unsigned short* A  = kT + ((size_t)b * D_ + d0) * N_ + kc * 2048;
  const unsigned short* Bp = vT + ((size_t)b * D_ + e0) * N_ + kc * 2048;
  int t = threadIdx.x, lane = t & 63, wid = t >> 6, wm = wid >> 1, wn = wid & 1;
  f32x4 acc[4][4] = {};
  stage8(A, Bp, N_, N_, LA[0], LB[0], t, 0);
  asm volatile("s_waitcnt vmcnt(0)" ::: "memory");
  __syncthreads();
  int cur = 0;
  for (int it = 0; it < 32; ++it) {
    if (it < 31) stage8(A, Bp, N_, N_, LA[cur ^ 1], LB[cur ^ 1], t, (it + 1) * 64);
    mac128(LA[cur], LB[cur], lane, wm, wn, acc);
    asm volatile("s_waitcnt vmcnt(0)" ::: "memory");
    __syncthreads();
    cur ^= 1;
  }
  float* P = part + ((size_t)(kc * 4 + b) << 20) + (size_t)d0 * D_ + e0;
  int rq = (lane >> 4) * 4, cc = lane & 15;
  #pragma unroll
  for (int m = 0; m < 4; ++m)
    #pragma unroll
    for (int r = 0; r < 4; ++r) {
      int row = wm * 64 + m * 16 + rq + r;
      #pragma unroll
      for (int n = 0; n < 4; ++n)
        P[(size_t)row * D_ + wn * 64 + n * 16 + cc] = acc[m][n][r];
    }
}

// ---------------- reduce + denom tail blocks ----------------
// bid < 1024: kvT[b,e,d] = bf16(part0+part1), transposed via LDS.
// bid >= 1024 (4096 blocks): den[b,n] = sum_d q'_bf16 * ksum.
__global__ __launch_bounds__(256) void k_rd(const float* __restrict__ part,
                                            unsigned short* __restrict__ kvT,
                                            const unsigned short* __restrict__ qp,
                                            const float* __restrict__ ksum,
                                            float* __restrict__ den) {
  __shared__ unsigned T[64 * 36];              // [e][36] dwords: 32 d-pair dwords + 4 pad
  int bid = blockIdx.x;
  if (bid >= 1024) {                           // ---- denom path ----
    int wid = threadIdx.x >> 6, lane = threadIdx.x & 63;
    int row = (bid - 1024) * 4 + wid;          // [0, B*N)
    int b = row >> 12;
    const unsigned short* qr = qp + (size_t)row * D_ + lane * 16;
    const float* ks = ksum + b * D_ + lane * 16;
    s16x8 h0 = *(const s16x8*)qr;
    s16x8 h1 = *(const s16x8*)(qr + 8);
    float acc = 0.f;
    #pragma unroll
    for (int j = 0; j < 8; ++j) acc += bf2f((unsigned short)h0[j]) * ks[j];
    #pragma unroll
    for (int j = 0; j < 8; ++j) acc += bf2f((unsigned short)h1[j]) * ks[8 + j];
    #pragma unroll
    for (int o = 32; o; o >>= 1) acc += __shfl_down(acc, o, 64);
    if (!lane) den[row] = acc;
    return;
  }
  // ---- reduce path (dword-pair LDS transpose) ----
  int b = bid >> 8, eb = (bid >> 4) & 15, db = bid & 15;
  const float* p0 = part + ((size_t)b << 20) + (size_t)(db * 64) * D_ + eb * 64;
  const float* p1 = p0 + ((size_t)4 << 20);
  int t = threadIdx.x;
  int d0 = (t >> 4) * 4, ec = (t & 15) * 4;    // wave reads 256B/row
  f32x4 a0 = *(const f32x4*)(p0 + (size_t)d0 * D_ + ec)       + *(const f32x4*)(p1 + (size_t)d0 * D_ + ec);
  f32x4 a1 = *(const f32x4*)(p0 + (size_t)(d0 + 1) * D_ + ec) + *(const f32x4*)(p1 + (size_t)(d0 + 1) * D_ + ec);
  f32x4 a2 = *(const f32x4*)(p0 + (size_t)(d0 + 2) * D_ + ec) + *(const f32x4*)(p1 + (size_t)(d0 + 2) * D_ + ec);
  f32x4 a3 = *(const f32x4*)(p0 + (size_t)(d0 + 3) * D_ + ec) + *(const f32x4*)(p1 + (size_t)(d0 + 3) * D_ + ec);
  #pragma unroll
  for (int j = 0; j < 4; ++j) {
    unsigned lo = (unsigned)f2bf(a0[j]) | ((unsigned)f2bf(a1[j]) << 16);
    unsigned hi = (unsigned)f2bf(a2[j]) | ((unsigned)f2bf(a3[j]) << 16);
    *(unsigned long long*)&T[(ec + j) * 36 + d0 / 2] =
        (unsigned long long)lo | ((unsigned long long)hi << 32);
  }
  __syncthreads();
  int e = t >> 2, cc = t & 3;
  unsigned short* dstb = kvT + ((size_t)b * D_ + eb * 64 + e) * D_ + db * 64;
  #pragma unroll
  for (int m = 0; m < 2; ++m) {
    s16x8 w = *(const s16x8*)&T[e * 36 + cc * 8 + m * 4];
    *(s16x8*)(dstb + cc * 16 + m * 8) = w;
  }
}

// ---------------- GEMM2: out[b,n,e] = (sum_d q'[n,d] kvT[e,d]) / (den+eps) ----------------
__global__ __launch_bounds__(256, 2) void k_gemm2(const unsigned short* __restrict__ qp,
                                                  const unsigned short* __restrict__ kvT,
                                                  const float* __restrict__ den,
                                                  float* __restrict__ out) {
  __shared__ unsigned short LA[2][8192], LB[2][8192];
  int bid = blockIdx.x;
  int b = (bid & 7) >> 1, mh = bid & 1, sg = bid >> 3;
  int ml = sg & 15, e = sg >> 4;
  int m0 = (mh * 16 + ml) * 128, e0 = e * 128;
  const unsigned short* A  = qp  + ((size_t)b * N_ + m0) * D_;
  const unsigned short* Bp = kvT + ((size_t)b * D_ + e0) * D_;
  int t = threadIdx.x, lane = t & 63, wid = t >> 6, wm = wid >> 1, wn = wid & 1;
  f32x4 acc[4][4] = {};
  stage8(A, Bp, D_, D_, LA[0], LB[0], t, 0);
  asm volatile("s_waitcnt vmcnt(0)" ::: "memory");
  __syncthreads();
  int cur = 0;
  for (int it = 0; it < 16; ++it) {
    if (it < 15) stage8(A, Bp, D_, D_, LA[cur ^ 1], LB[cur ^ 1], t, (it + 1) * 64);
    mac128(LA[cur], LB[cur], lane, wm, wn, acc);
    asm volatile("s_waitcnt vmcnt(0)" ::: "memory");
    __syncthreads();
    cur ^= 1;
  }
  const float* dn = den + b * N_ + m0;
  float* ob = out + ((size_t)b * N_ + m0) * D_ + e0;
  int rq = (lane >> 4) * 4, cc = lane & 15;
  #pragma unroll
  for (int m = 0; m < 4; ++m)
    #pragma unroll
    for (int r = 0; r < 4; ++r) {
      int row = wm * 64 + m * 16 + rq + r;
      float inv = 1.f / (dn[row] + 1e-6f);
      #pragma unroll
      for (int n = 0; n < 4; ++n)
        ob[(size_t)row * D_ + wn * 64 + n * 16 + cc] = acc[m][n][r] * inv;
    }
}

extern "C" void kernel_launch(void* const* d_in, const int* in_sizes, int n_in,
                              void* d_out, int out_size, void* d_ws, size_t ws_size,
                              hipStream_t stream) {
  const float* q = (const float*)d_in[0];
  const float* k = (const float*)d_in[1];
  const float* v = (const float*)d_in[2];
  float* outF = (float*)d_out;
  char* ws = (char*)d_ws;

  // ws: qp 32MB | kT 32MB | vT 32MB | kvT 8MB | ksum 16KB | den 64KB  (= 104.1MB)
  unsigned short* qp  = (unsigned short*)ws;
  unsigned short* kT  = (unsigned short*)(ws + ((size_t)32 << 20));
  unsigned short* vT  = (unsigned short*)(ws + ((size_t)64 << 20));
  unsigned short* kvT = (unsigned short*)(ws + ((size_t)96 << 20));
  float* ksum = (float*)(ws + ((size_t)104 << 20));
  float* den  = (float*)(ws + ((size_t)104 << 20) + 16384);
  // d_out doubles as scratch (fully overwritten by k_gemm2 afterwards):
  float* part   = outF;                 // 2 x 16MB fp32 kv partials
  float* kspart = outF + (8 << 20);     // 1MB ksum partials at +32MB

  k_prep <<<9216, 256, 0, stream>>>(q, k, v, qp, kT, vT, kspart);
  k_g1   <<<528, 256, 0, stream>>>(kT, vT, part, kspart, ksum);
  k_rd   <<<5120, 256, 0, stream>>>(part, kvT, qp, ksum, den);
  k_gemm2<<<1024, 256, 0, stream>>>(qp, kvT, den, outF);
}